// Round 2
// baseline (6280.303 us; speedup 1.0000x reference)
//
#include <hip/hip_runtime.h>
#include <math.h>

#define N_NODES 100000
#define N_EDGES 3200000
#define NFEAT 512
#define NHID 256
#define NCLASS 16
#define NLAYERS 8

#define SCAN_CHUNK 1024
#define NB ((N_NODES + SCAN_CHUNK - 1) / SCAN_CHUNK)   // 98

// ---------------- CSR build ----------------
__global__ void k_hist(const int* __restrict__ dst, int* __restrict__ cnt) {
  int i = blockIdx.x * 256 + threadIdx.x;
  if (i < N_EDGES) atomicAdd(&cnt[dst[i]], 1);
}

__global__ void k_blocksum(const int* __restrict__ cnt, int* __restrict__ bs) {
  __shared__ int red[256];
  int b = blockIdx.x, t = threadIdx.x;
  int s = 0;
  int base = b * SCAN_CHUNK;
  for (int j = 0; j < 4; ++j) {
    int i = base + t + j * 256;
    if (i < N_NODES) s += cnt[i];
  }
  red[t] = s;
  __syncthreads();
  for (int off = 128; off > 0; off >>= 1) {
    if (t < off) red[t] += red[t + off];
    __syncthreads();
  }
  if (t == 0) bs[b] = red[0];
}

__global__ void k_scan_top(int* __restrict__ bs, int* __restrict__ rp) {
  if (threadIdx.x == 0) {
    int run = 0;
    for (int b = 0; b < NB; ++b) { int v = bs[b]; bs[b] = run; run += v; }
    rp[N_NODES] = run;   // == N_EDGES
  }
}

__global__ void k_scan_write(const int* __restrict__ cnt, const int* __restrict__ bs,
                             int* __restrict__ rp) {
  __shared__ int tot[256];
  int b = blockIdx.x, t = threadIdx.x;
  int base = b * SCAN_CHUNK + t * 4;
  int v0 = 0, v1 = 0, v2 = 0, v3 = 0;
  if (base + 0 < N_NODES) v0 = cnt[base + 0];
  if (base + 1 < N_NODES) v1 = cnt[base + 1];
  if (base + 2 < N_NODES) v2 = cnt[base + 2];
  if (base + 3 < N_NODES) v3 = cnt[base + 3];
  int tsum = v0 + v1 + v2 + v3;
  tot[t] = tsum;
  __syncthreads();
  // inclusive Hillis-Steele over 256 per-thread totals
  for (int off = 1; off < 256; off <<= 1) {
    int val = 0;
    if (t >= off) val = tot[t - off];
    __syncthreads();
    if (t >= off) tot[t] += val;
    __syncthreads();
  }
  int excl = tot[t] - tsum + bs[b];
  if (base + 0 < N_NODES) rp[base + 0] = excl;
  if (base + 1 < N_NODES) rp[base + 1] = excl + v0;
  if (base + 2 < N_NODES) rp[base + 2] = excl + v0 + v1;
  if (base + 3 < N_NODES) rp[base + 3] = excl + v0 + v1 + v2;
}

__global__ void k_fill(const int* __restrict__ src, const int* __restrict__ dst,
                       const float* __restrict__ w, const int* __restrict__ rp,
                       int* __restrict__ fill, int* __restrict__ col,
                       float* __restrict__ val) {
  int i = blockIdx.x * 256 + threadIdx.x;
  if (i < N_EDGES) {
    int d = dst[i];
    int pos = rp[d] + atomicAdd(&fill[d], 1);
    col[pos] = src[i];
    val[pos] = w[i];
  }
}

// ---------------- SpMM + fused support ----------------
// one wave per dst node; lane owns 4 consecutive feats (float4)
// sup[d] = 0.9 * sum_e w_e * h[src_e] + 0.1 * h0[d]
// Unroll-8 edge loop: 8 independent 1KB row-gathers in flight per wave
// (round-1 showed VALUBusy 11% @ 82% occupancy -> chained-latency bound).
__global__ __launch_bounds__(256)
void k_spmm(const int* __restrict__ rp, const int* __restrict__ col,
            const float* __restrict__ val, const float* __restrict__ h,
            const float* __restrict__ h0, float* __restrict__ sup) {
  int wave = threadIdx.x >> 6;
  int lane = threadIdx.x & 63;
  int node = blockIdx.x * 4 + wave;
  if (node >= N_NODES) return;
  int e0 = rp[node], e1 = rp[node + 1];
  const float4* __restrict__ hv = (const float4*)h;   // row stride 64 float4

  float4 a0 = make_float4(0.f, 0.f, 0.f, 0.f);
  float4 a1 = make_float4(0.f, 0.f, 0.f, 0.f);
  float4 a2 = make_float4(0.f, 0.f, 0.f, 0.f);
  float4 a3 = make_float4(0.f, 0.f, 0.f, 0.f);

  int e = e0;
  for (; e + 8 <= e1; e += 8) {
    int   s[8];
    float w[8];
#pragma unroll
    for (int j = 0; j < 8; ++j) { s[j] = col[e + j]; w[j] = val[e + j]; }
    float4 v[8];
#pragma unroll
    for (int j = 0; j < 8; ++j) v[j] = hv[(size_t)s[j] * 64 + lane];
#pragma unroll
    for (int j = 0; j < 8; ++j) {
      float4* a = (j & 3) == 0 ? &a0 : (j & 3) == 1 ? &a1 : (j & 3) == 2 ? &a2 : &a3;
      a->x += w[j] * v[j].x; a->y += w[j] * v[j].y;
      a->z += w[j] * v[j].z; a->w += w[j] * v[j].w;
    }
  }
  // remainder (<8), keep 2 in flight
  for (; e + 2 <= e1; e += 2) {
    int s0 = col[e], s1 = col[e + 1];
    float w0 = val[e], w1 = val[e + 1];
    float4 v0 = hv[(size_t)s0 * 64 + lane];
    float4 v1 = hv[(size_t)s1 * 64 + lane];
    a0.x += w0 * v0.x; a0.y += w0 * v0.y; a0.z += w0 * v0.z; a0.w += w0 * v0.w;
    a1.x += w1 * v1.x; a1.y += w1 * v1.y; a1.z += w1 * v1.z; a1.w += w1 * v1.w;
  }
  if (e < e1) {
    int s0 = col[e];
    float w0 = val[e];
    float4 v0 = hv[(size_t)s0 * 64 + lane];
    a0.x += w0 * v0.x; a0.y += w0 * v0.y; a0.z += w0 * v0.z; a0.w += w0 * v0.w;
  }

  float4 acc;
  acc.x = (a0.x + a1.x) + (a2.x + a3.x);
  acc.y = (a0.y + a1.y) + (a2.y + a3.y);
  acc.z = (a0.z + a1.z) + (a2.z + a3.z);
  acc.w = (a0.w + a1.w) + (a2.w + a3.w);

  float4 z = ((const float4*)h0)[(size_t)node * 64 + lane];
  float4 o;
  o.x = 0.9f * acc.x + 0.1f * z.x;
  o.y = 0.9f * acc.y + 0.1f * z.y;
  o.z = 0.9f * acc.z + 0.1f * z.z;
  o.w = 0.9f * acc.w + 0.1f * z.w;
  ((float4*)sup)[(size_t)node * 64 + lane] = o;
}

// ---------------- GEMM, 128x128 tile, BK=16, 8x8 micro-tile ----------------
// MODE 0: out1 = out2 = relu(A@W + bias)            (A = x, K = 512)
// MODE 1: out1 = relu(theta*(A@W) + (1-theta)*A + hin)   (A = sup, K = 256, in-place h)
template <int MODE>
__global__ __launch_bounds__(256)
void k_gemm(const float* __restrict__ A, const float* __restrict__ W, int K,
            const float* __restrict__ bias, const float* __restrict__ hin,
            float* __restrict__ out1, float* __restrict__ out2, float theta) {
  __shared__ float As[16][128];
  __shared__ float Bs[16][128];
  int bm = blockIdx.x * 128, bn = blockIdx.y * 128;
  int tid = threadIdx.x;
  int tx = tid & 15, ty = tid >> 4;
  float acc[8][8];
#pragma unroll
  for (int i = 0; i < 8; ++i)
#pragma unroll
    for (int j = 0; j < 8; ++j) acc[i][j] = 0.f;

  for (int kc = 0; kc < K; kc += 16) {
    // stage A tile (transposed into As[k][m])
#pragma unroll
    for (int it = 0; it < 2; ++it) {
      int idx = tid + it * 256;        // 0..511
      int m = idx >> 2, q = (idx & 3) * 4;
      int gm = bm + m;
      float4 f = make_float4(0.f, 0.f, 0.f, 0.f);
      if (gm < N_NODES) f = *(const float4*)&A[(size_t)gm * K + kc + q];
      As[q + 0][m] = f.x; As[q + 1][m] = f.y; As[q + 2][m] = f.z; As[q + 3][m] = f.w;
    }
    // stage B tile (row-major copy)
#pragma unroll
    for (int it = 0; it < 2; ++it) {
      int idx = tid + it * 256;        // 0..511
      int kk = idx >> 5, nq = (idx & 31) * 4;
      *(float4*)&Bs[kk][nq] = *(const float4*)&W[(size_t)(kc + kk) * NHID + bn + nq];
    }
    __syncthreads();
#pragma unroll
    for (int k = 0; k < 16; ++k) {
      float a[8], b[8];
      *(float4*)&a[0] = *(const float4*)&As[k][ty * 8];
      *(float4*)&a[4] = *(const float4*)&As[k][ty * 8 + 4];
      *(float4*)&b[0] = *(const float4*)&Bs[k][tx * 8];
      *(float4*)&b[4] = *(const float4*)&Bs[k][tx * 8 + 4];
#pragma unroll
      for (int i = 0; i < 8; ++i)
#pragma unroll
        for (int j = 0; j < 8; ++j) acc[i][j] += a[i] * b[j];
    }
    __syncthreads();
  }

  // epilogue
#pragma unroll
  for (int i = 0; i < 8; ++i) {
    int gm = bm + ty * 8 + i;
    if (gm >= N_NODES) continue;
    size_t rowo = (size_t)gm * NHID + bn + tx * 8;
    if (MODE == 0) {
#pragma unroll
      for (int j = 0; j < 8; ++j) {
        float v = acc[i][j] + bias[bn + tx * 8 + j];
        v = fmaxf(v, 0.f);
        out1[rowo + j] = v;
        out2[rowo + j] = v;
      }
    } else {
      float omt = 1.f - theta;
#pragma unroll
      for (int j = 0; j < 8; ++j) {
        float s = A[rowo + j];       // support (K==NHID==256, same layout)
        float hv = hin[rowo + j];
        float v = theta * acc[i][j] + omt * s + hv;
        out1[rowo + j] = fmaxf(v, 0.f);
      }
    }
  }
}

// ---------------- head: out = sigmoid(h @ w1 + b1) ----------------
__global__ __launch_bounds__(256)
void k_final(const float* __restrict__ h, const float* __restrict__ w1,
             const float* __restrict__ b1, float* __restrict__ out) {
  __shared__ float ws[NHID * NCLASS];
  int t = threadIdx.x;
  for (int i = t; i < NHID * NCLASS; i += 256) ws[i] = w1[i];
  __syncthreads();
  int node = blockIdx.x * 16 + (t >> 4);
  int c = t & 15;
  if (node >= N_NODES) return;
  float acc = b1[c];
  const float* hr = &h[(size_t)node * NHID];
  for (int k = 0; k < NHID; k += 4) {
    float4 hv = *(const float4*)&hr[k];
    acc += hv.x * ws[(k + 0) * NCLASS + c];
    acc += hv.y * ws[(k + 1) * NCLASS + c];
    acc += hv.z * ws[(k + 2) * NCLASS + c];
    acc += hv.w * ws[(k + 3) * NCLASS + c];
  }
  out[(size_t)node * NCLASS + c] = 1.f / (1.f + __expf(-acc));
}

// ---------------- host ----------------
extern "C" void kernel_launch(void* const* d_in, const int* in_sizes, int n_in,
                              void* d_out, int out_size, void* d_ws, size_t ws_size,
                              hipStream_t stream) {
  const float* x        = (const float*)d_in[0];
  const int*   edge_src = (const int*)d_in[1];
  const int*   edge_dst = (const int*)d_in[2];
  const float* edge_w   = (const float*)d_in[3];
  const float* w0       = (const float*)d_in[4];
  const float* b0       = (const float*)d_in[5];
  const float* conv_w   = (const float*)d_in[6];
  const float* w1       = (const float*)d_in[7];
  const float* b1       = (const float*)d_in[8];
  float* out = (float*)d_out;

  // workspace layout (256B aligned)
  char* ws = (char*)d_ws;
  size_t off = 0;
  auto alloc = [&](size_t bytes) {
    size_t o = off;
    off = (off + bytes + 255) & ~(size_t)255;
    return (void*)(ws + o);
  };
  float* h   = (float*)alloc((size_t)N_NODES * NHID * 4);
  float* h0  = (float*)alloc((size_t)N_NODES * NHID * 4);
  float* sup = (float*)alloc((size_t)N_NODES * NHID * 4);
  int*   rp  = (int*)alloc((size_t)(N_NODES + 1) * 4);
  int*   cnt = (int*)alloc((size_t)N_NODES * 4);
  int*   col = (int*)alloc((size_t)N_EDGES * 4);
  float* val = (float*)alloc((size_t)N_EDGES * 4);
  int*   bs  = (int*)alloc((size_t)NB * 4);
  (void)ws_size;

  // ---- CSR build ----
  hipMemsetAsync(cnt, 0, (size_t)N_NODES * 4, stream);
  k_hist<<<(N_EDGES + 255) / 256, 256, 0, stream>>>(edge_dst, cnt);
  k_blocksum<<<NB, 256, 0, stream>>>(cnt, bs);
  k_scan_top<<<1, 64, 0, stream>>>(bs, rp);
  k_scan_write<<<NB, 256, 0, stream>>>(cnt, bs, rp);
  hipMemsetAsync(cnt, 0, (size_t)N_NODES * 4, stream);
  k_fill<<<(N_EDGES + 255) / 256, 256, 0, stream>>>(edge_src, edge_dst, edge_w, rp,
                                                    cnt, col, val);

  // ---- h = relu(x@w0 + b0); h0 = h ----
  dim3 g0((N_NODES + 127) / 128, NHID / 128);
  k_gemm<0><<<g0, 256, 0, stream>>>(x, w0, NFEAT, b0, nullptr, h, h0, 0.f);

  // ---- 8 GCNII layers ----
  for (int i = 0; i < NLAYERS; ++i) {
    float theta = logf(0.5f / (float)(i + 1) + 1.0f);
    k_spmm<<<(N_NODES + 3) / 4, 256, 0, stream>>>(rp, col, val, h, h0, sup);
    const float* cw = conv_w + (size_t)i * NHID * NHID;
    k_gemm<1><<<g0, 256, 0, stream>>>(sup, cw, NHID, nullptr, h, h, nullptr, theta);
  }

  // ---- head ----
  k_final<<<(N_NODES + 15) / 16, 256, 0, stream>>>(h, w1, b1, out);
}

// Round 3
// 6098.140 us; speedup vs baseline: 1.0299x; 1.0299x over previous
//
#include <hip/hip_runtime.h>
#include <math.h>

#define N_NODES 100000
#define N_EDGES 3200000
#define NFEAT 512
#define NHID 256
#define NCLASS 16
#define NLAYERS 8

#define SCAN_CHUNK 1024
#define NB ((N_NODES + SCAN_CHUNK - 1) / SCAN_CHUNK)   // 98

// ---------------- CSR build ----------------
__global__ void k_hist(const int* __restrict__ dst, int* __restrict__ cnt) {
  int i = blockIdx.x * 256 + threadIdx.x;
  if (i < N_EDGES) atomicAdd(&cnt[dst[i]], 1);
}

__global__ void k_blocksum(const int* __restrict__ cnt, int* __restrict__ bs) {
  __shared__ int red[256];
  int b = blockIdx.x, t = threadIdx.x;
  int s = 0;
  int base = b * SCAN_CHUNK;
  for (int j = 0; j < 4; ++j) {
    int i = base + t + j * 256;
    if (i < N_NODES) s += cnt[i];
  }
  red[t] = s;
  __syncthreads();
  for (int off = 128; off > 0; off >>= 1) {
    if (t < off) red[t] += red[t + off];
    __syncthreads();
  }
  if (t == 0) bs[b] = red[0];
}

__global__ void k_scan_top(int* __restrict__ bs, int* __restrict__ rp) {
  if (threadIdx.x == 0) {
    int run = 0;
    for (int b = 0; b < NB; ++b) { int v = bs[b]; bs[b] = run; run += v; }
    rp[N_NODES] = run;   // == N_EDGES
  }
}

__global__ void k_scan_write(const int* __restrict__ cnt, const int* __restrict__ bs,
                             int* __restrict__ rp) {
  __shared__ int tot[256];
  int b = blockIdx.x, t = threadIdx.x;
  int base = b * SCAN_CHUNK + t * 4;
  int v0 = 0, v1 = 0, v2 = 0, v3 = 0;
  if (base + 0 < N_NODES) v0 = cnt[base + 0];
  if (base + 1 < N_NODES) v1 = cnt[base + 1];
  if (base + 2 < N_NODES) v2 = cnt[base + 2];
  if (base + 3 < N_NODES) v3 = cnt[base + 3];
  int tsum = v0 + v1 + v2 + v3;
  tot[t] = tsum;
  __syncthreads();
  // inclusive Hillis-Steele over 256 per-thread totals
  for (int off = 1; off < 256; off <<= 1) {
    int val = 0;
    if (t >= off) val = tot[t - off];
    __syncthreads();
    if (t >= off) tot[t] += val;
    __syncthreads();
  }
  int excl = tot[t] - tsum + bs[b];
  if (base + 0 < N_NODES) rp[base + 0] = excl;
  if (base + 1 < N_NODES) rp[base + 1] = excl + v0;
  if (base + 2 < N_NODES) rp[base + 2] = excl + v0 + v1;
  if (base + 3 < N_NODES) rp[base + 3] = excl + v0 + v1 + v2;
}

__global__ void k_fill(const int* __restrict__ src, const int* __restrict__ dst,
                       const float* __restrict__ w, const int* __restrict__ rp,
                       int* __restrict__ fill, int* __restrict__ col,
                       float* __restrict__ val) {
  int i = blockIdx.x * 256 + threadIdx.x;
  if (i < N_EDGES) {
    int d = dst[i];
    int pos = rp[d] + atomicAdd(&fill[d], 1);
    col[pos] = src[i];
    val[pos] = w[i];
  }
}

// ---------------- SpMM + fused support, feature-split ----------------
// Processes feature half [f0, f0+128). Per-pass working set (h/2 + h0/2 +
// sup/2 + col/val = 179 MB) fits the 256 MB L3, so the random h-row gathers
// hit L3 instead of thrashing to HBM (round-2: 1.68 GB FETCH vs 230 MB
// compulsory at full width).
// One wave per dst node; lane owns one float2 (64 x 8B = 512B/row-gather).
__global__ __launch_bounds__(256)
void k_spmm_half(const int* __restrict__ rp, const int* __restrict__ col,
                 const float* __restrict__ val, const float* __restrict__ h,
                 const float* __restrict__ h0, float* __restrict__ sup, int f0) {
  int wave = threadIdx.x >> 6;
  int lane = threadIdx.x & 63;
  int node = blockIdx.x * 4 + wave;
  if (node >= N_NODES) return;
  int e0 = rp[node], e1 = rp[node + 1];
  const float2* __restrict__ hv = (const float2*)h;  // row stride 128 float2
  int fo = (f0 >> 1) + lane;                          // float2 index within row

  float2 a0 = make_float2(0.f, 0.f);
  float2 a1 = make_float2(0.f, 0.f);
  float2 a2 = make_float2(0.f, 0.f);
  float2 a3 = make_float2(0.f, 0.f);

  int e = e0;
  for (; e + 4 <= e1; e += 4) {
    int s0 = col[e], s1 = col[e + 1], s2 = col[e + 2], s3 = col[e + 3];
    float w0 = val[e], w1 = val[e + 1], w2 = val[e + 2], w3 = val[e + 3];
    float2 v0 = hv[(size_t)s0 * 128 + fo];
    float2 v1 = hv[(size_t)s1 * 128 + fo];
    float2 v2 = hv[(size_t)s2 * 128 + fo];
    float2 v3 = hv[(size_t)s3 * 128 + fo];
    a0.x += w0 * v0.x; a0.y += w0 * v0.y;
    a1.x += w1 * v1.x; a1.y += w1 * v1.y;
    a2.x += w2 * v2.x; a2.y += w2 * v2.y;
    a3.x += w3 * v3.x; a3.y += w3 * v3.y;
  }
  for (; e < e1; ++e) {
    int s0 = col[e];
    float w0 = val[e];
    float2 v0 = hv[(size_t)s0 * 128 + fo];
    a0.x += w0 * v0.x; a0.y += w0 * v0.y;
  }

  float2 acc;
  acc.x = (a0.x + a1.x) + (a2.x + a3.x);
  acc.y = (a0.y + a1.y) + (a2.y + a3.y);

  float2 z = ((const float2*)h0)[(size_t)node * 128 + fo];
  float2 o;
  o.x = 0.9f * acc.x + 0.1f * z.x;
  o.y = 0.9f * acc.y + 0.1f * z.y;
  ((float2*)sup)[(size_t)node * 128 + fo] = o;
}

// ---------------- GEMM, 128x128 tile, BK=16, 8x8 micro-tile ----------------
// MODE 0: out1 = out2 = relu(A@W + bias)            (A = x, K = 512)
// MODE 1: out1 = relu(theta*(A@W) + (1-theta)*A + hin)   (A = sup, K = 256, in-place h)
template <int MODE>
__global__ __launch_bounds__(256)
void k_gemm(const float* __restrict__ A, const float* __restrict__ W, int K,
            const float* __restrict__ bias, const float* __restrict__ hin,
            float* __restrict__ out1, float* __restrict__ out2, float theta) {
  __shared__ float As[16][128];
  __shared__ float Bs[16][128];
  int bm = blockIdx.x * 128, bn = blockIdx.y * 128;
  int tid = threadIdx.x;
  int tx = tid & 15, ty = tid >> 4;
  float acc[8][8];
#pragma unroll
  for (int i = 0; i < 8; ++i)
#pragma unroll
    for (int j = 0; j < 8; ++j) acc[i][j] = 0.f;

  for (int kc = 0; kc < K; kc += 16) {
    // stage A tile (transposed into As[k][m])
#pragma unroll
    for (int it = 0; it < 2; ++it) {
      int idx = tid + it * 256;        // 0..511
      int m = idx >> 2, q = (idx & 3) * 4;
      int gm = bm + m;
      float4 f = make_float4(0.f, 0.f, 0.f, 0.f);
      if (gm < N_NODES) f = *(const float4*)&A[(size_t)gm * K + kc + q];
      As[q + 0][m] = f.x; As[q + 1][m] = f.y; As[q + 2][m] = f.z; As[q + 3][m] = f.w;
    }
    // stage B tile (row-major copy)
#pragma unroll
    for (int it = 0; it < 2; ++it) {
      int idx = tid + it * 256;        // 0..511
      int kk = idx >> 5, nq = (idx & 31) * 4;
      *(float4*)&Bs[kk][nq] = *(const float4*)&W[(size_t)(kc + kk) * NHID + bn + nq];
    }
    __syncthreads();
#pragma unroll
    for (int k = 0; k < 16; ++k) {
      float a[8], b[8];
      *(float4*)&a[0] = *(const float4*)&As[k][ty * 8];
      *(float4*)&a[4] = *(const float4*)&As[k][ty * 8 + 4];
      *(float4*)&b[0] = *(const float4*)&Bs[k][tx * 8];
      *(float4*)&b[4] = *(const float4*)&Bs[k][tx * 8 + 4];
#pragma unroll
      for (int i = 0; i < 8; ++i)
#pragma unroll
        for (int j = 0; j < 8; ++j) acc[i][j] += a[i] * b[j];
    }
    __syncthreads();
  }

  // epilogue
#pragma unroll
  for (int i = 0; i < 8; ++i) {
    int gm = bm + ty * 8 + i;
    if (gm >= N_NODES) continue;
    size_t rowo = (size_t)gm * NHID + bn + tx * 8;
    if (MODE == 0) {
#pragma unroll
      for (int j = 0; j < 8; ++j) {
        float v = acc[i][j] + bias[bn + tx * 8 + j];
        v = fmaxf(v, 0.f);
        out1[rowo + j] = v;
        out2[rowo + j] = v;
      }
    } else {
      float omt = 1.f - theta;
#pragma unroll
      for (int j = 0; j < 8; ++j) {
        float s = A[rowo + j];       // support (K==NHID==256, same layout)
        float hv = hin[rowo + j];
        float v = theta * acc[i][j] + omt * s + hv;
        out1[rowo + j] = fmaxf(v, 0.f);
      }
    }
  }
}

// ---------------- head: out = sigmoid(h @ w1 + b1) ----------------
__global__ __launch_bounds__(256)
void k_final(const float* __restrict__ h, const float* __restrict__ w1,
             const float* __restrict__ b1, float* __restrict__ out) {
  __shared__ float ws[NHID * NCLASS];
  int t = threadIdx.x;
  for (int i = t; i < NHID * NCLASS; i += 256) ws[i] = w1[i];
  __syncthreads();
  int node = blockIdx.x * 16 + (t >> 4);
  int c = t & 15;
  if (node >= N_NODES) return;
  float acc = b1[c];
  const float* hr = &h[(size_t)node * NHID];
  for (int k = 0; k < NHID; k += 4) {
    float4 hv = *(const float4*)&hr[k];
    acc += hv.x * ws[(k + 0) * NCLASS + c];
    acc += hv.y * ws[(k + 1) * NCLASS + c];
    acc += hv.z * ws[(k + 2) * NCLASS + c];
    acc += hv.w * ws[(k + 3) * NCLASS + c];
  }
  out[(size_t)node * NCLASS + c] = 1.f / (1.f + __expf(-acc));
}

// ---------------- host ----------------
extern "C" void kernel_launch(void* const* d_in, const int* in_sizes, int n_in,
                              void* d_out, int out_size, void* d_ws, size_t ws_size,
                              hipStream_t stream) {
  const float* x        = (const float*)d_in[0];
  const int*   edge_src = (const int*)d_in[1];
  const int*   edge_dst = (const int*)d_in[2];
  const float* edge_w   = (const float*)d_in[3];
  const float* w0       = (const float*)d_in[4];
  const float* b0       = (const float*)d_in[5];
  const float* conv_w   = (const float*)d_in[6];
  const float* w1       = (const float*)d_in[7];
  const float* b1       = (const float*)d_in[8];
  float* out = (float*)d_out;

  // workspace layout (256B aligned)
  char* ws = (char*)d_ws;
  size_t off = 0;
  auto alloc = [&](size_t bytes) {
    size_t o = off;
    off = (off + bytes + 255) & ~(size_t)255;
    return (void*)(ws + o);
  };
  float* h   = (float*)alloc((size_t)N_NODES * NHID * 4);
  float* h0  = (float*)alloc((size_t)N_NODES * NHID * 4);
  float* sup = (float*)alloc((size_t)N_NODES * NHID * 4);
  int*   rp  = (int*)alloc((size_t)(N_NODES + 1) * 4);
  int*   cnt = (int*)alloc((size_t)N_NODES * 4);
  int*   col = (int*)alloc((size_t)N_EDGES * 4);
  float* val = (float*)alloc((size_t)N_EDGES * 4);
  int*   bs  = (int*)alloc((size_t)NB * 4);
  (void)ws_size;

  // ---- CSR build ----
  hipMemsetAsync(cnt, 0, (size_t)N_NODES * 4, stream);
  k_hist<<<(N_EDGES + 255) / 256, 256, 0, stream>>>(edge_dst, cnt);
  k_blocksum<<<NB, 256, 0, stream>>>(cnt, bs);
  k_scan_top<<<1, 64, 0, stream>>>(bs, rp);
  k_scan_write<<<NB, 256, 0, stream>>>(cnt, bs, rp);
  hipMemsetAsync(cnt, 0, (size_t)N_NODES * 4, stream);
  k_fill<<<(N_EDGES + 255) / 256, 256, 0, stream>>>(edge_src, edge_dst, edge_w, rp,
                                                    cnt, col, val);

  // ---- h = relu(x@w0 + b0); h0 = h ----
  dim3 g0((N_NODES + 127) / 128, NHID / 128);
  k_gemm<0><<<g0, 256, 0, stream>>>(x, w0, NFEAT, b0, nullptr, h, h0, 0.f);

  // ---- 8 GCNII layers ----
  for (int i = 0; i < NLAYERS; ++i) {
    float theta = logf(0.5f / (float)(i + 1) + 1.0f);
    k_spmm_half<<<(N_NODES + 3) / 4, 256, 0, stream>>>(rp, col, val, h, h0, sup, 0);
    k_spmm_half<<<(N_NODES + 3) / 4, 256, 0, stream>>>(rp, col, val, h, h0, sup, 128);
    const float* cw = conv_w + (size_t)i * NHID * NHID;
    k_gemm<1><<<g0, 256, 0, stream>>>(sup, cw, NHID, nullptr, h, h, nullptr, theta);
  }

  // ---- head ----
  k_final<<<(N_NODES + 15) / 16, 256, 0, stream>>>(h, w1, b1, out);
}